// Round 4
// baseline (137.986 us; speedup 1.0000x reference)
//
#include <hip/hip_runtime.h>
#include <hip/hip_bf16.h>

// Problem dims (fixed by setup_inputs): B=16, A=9, H=56, W=56, N=64.
// Output: (B, A*H*W, N) fp32 IoU matrix.
//
// R3 = R2 with the nontemporal-store type fixed (native clang vector type
// instead of HIP_vector_type struct).
//
// Design: two-phase block, wide stores.
//   Phase 1: 192 threads decode 192 proposals (one batch per block) into LDS
//            as {x0,y0,x1,y1} float4.
//   Phase 2: wave w owns proposals [w*64, w*64+64). Lane L: q=L>>4 selects
//            one of 4 proposals per iteration, g=L&15 selects bboxes 4g..4g+3.
//            Per iteration: one ds_read_b128 (broadcast x16) + ~51 VALU
//            + one nontemporal global_store_dwordx4 -> contiguous 1KB per
//            wave-inst, 256 outputs. 16 iterations cover the wave's 64 rows.
// Block=192 because 28224 (proposals/batch) = 147*192 -> no batch straddle.

constexpr int B_ = 16;
constexpr int A_ = 9;
constexpr int H_ = 56;
constexpr int W_ = 56;
constexpr int N_ = 64;
constexpr int HW_ = H_ * W_;            // 3136
constexpr int P_ = A_ * HW_;            // 28224 proposals per batch
constexpr int BLOCK = 192;              // 3 waves
constexpr int BLKS_PER_BATCH = P_ / BLOCK;  // 147

typedef float floatx4 __attribute__((ext_vector_type(4)));

__global__ __launch_bounds__(BLOCK) void ssd_iou_kernel(
    const float* __restrict__ anc,      // (A,2)
    const float* __restrict__ grid,     // (B,H,W,2)
    const float* __restrict__ offsets,  // (B,A,H,W,4)
    const float* __restrict__ bboxes,   // (B,N,5)
    float* __restrict__ out)            // (B, P, N)
{
    __shared__ float4 s_box[BLOCK];

    const int t  = threadIdx.x;
    const int b  = blockIdx.x / BLKS_PER_BATCH;           // batch (uniform)
    const int lb = blockIdx.x - b * BLKS_PER_BATCH;       // block within batch
    const int p0 = lb * BLOCK;                            // first local proposal

    // ---- Phase 1: decode one proposal per thread into LDS ----
    {
        const int lp = p0 + t;               // local proposal id in batch
        const int a  = lp / HW_;
        const int hw = lp - a * HW_;
        const int gp = b * P_ + lp;          // global proposal id

        const float4 off = reinterpret_cast<const float4*>(offsets)[gp];
        const float2 g   = reinterpret_cast<const float2*>(grid)[b * HW_ + hw];
        const float  aw  = anc[2 * a + 0];
        const float  ah  = anc[2 * a + 1];

        const float xc = g.x + off.x;
        const float yc = g.y + off.y;
        const float wp = aw * __expf(off.z);
        const float hp = ah * __expf(off.w);

        float4 box;
        box.x = xc - 0.5f * wp;   // x0
        box.y = yc - 0.5f * hp;   // y0
        box.z = xc + 0.5f * wp;   // x1
        box.w = yc + 0.5f * hp;   // y1
        s_box[t] = box;
    }
    __syncthreads();

    // ---- Phase 2 ----
    const int wave = t >> 6;
    const int lane = t & 63;
    const int q    = lane >> 4;   // proposal sub-index within group of 4
    const int g    = lane & 15;   // bbox group: bboxes 4g..4g+3

    // Per-lane bbox constants (4 boxes). 20KB total -> L1-resident.
    float bx0[4], by0[4], bx1[4], by1[4], aob[4];
    #pragma unroll
    for (int k = 0; k < 4; ++k) {
        const float* bb = bboxes + ((size_t)(b * N_ + 4 * g + k)) * 5;
        bx0[k] = bb[0];
        by0[k] = bb[1];
        bx1[k] = bb[2];
        by1[k] = bb[3];
        aob[k] = (bx1[k] - bx0[k]) * (by1[k] - by0[k]);
    }

    const int pbase = wave * 64;
    // out row for proposal p = pbase+4j+q, columns 4g..4g+3
    float* obase = out + ((size_t)(b * P_ + p0 + pbase + q)) * N_ + 4 * g;

    #pragma unroll 8
    for (int j = 0; j < 16; ++j) {
        const float4 pr = s_box[pbase + 4 * j + q];
        const float aop = (pr.z - pr.x) * (pr.w - pr.y);

        floatx4 res;
        #pragma unroll
        for (int k = 0; k < 4; ++k) {
            const float tlx = fmaxf(pr.x, bx0[k]);
            const float tly = fmaxf(pr.y, by0[k]);
            const float brx = fminf(pr.z, bx1[k]);
            const float bry = fminf(pr.w, by1[k]);

            const float iw  = fmaxf(brx - tlx, 0.0f);
            const float ih  = fmaxf(bry - tly, 0.0f);
            const float aoi = iw * ih;

            const float denom = aop + aob[k] - aoi;
            res[k] = aoi * __builtin_amdgcn_rcpf(denom);
        }

        __builtin_nontemporal_store(res,
            reinterpret_cast<floatx4*>(obase + (size_t)(4 * j) * N_));
    }
}

extern "C" void kernel_launch(void* const* d_in, const int* in_sizes, int n_in,
                              void* d_out, int out_size, void* d_ws, size_t ws_size,
                              hipStream_t stream) {
    const float* anc     = (const float*)d_in[0];
    const float* grid    = (const float*)d_in[1];
    const float* offsets = (const float*)d_in[2];
    const float* bboxes  = (const float*)d_in[3];
    float* out = (float*)d_out;

    const int nblocks = B_ * BLKS_PER_BATCH;   // 2352
    ssd_iou_kernel<<<nblocks, BLOCK, 0, stream>>>(anc, grid, offsets, bboxes, out);
}

// Round 5
// 130.772 us; speedup vs baseline: 1.0552x; 1.0552x over previous
//
#include <hip/hip_runtime.h>
#include <hip/hip_bf16.h>

// Problem dims (fixed by setup_inputs): B=16, A=9, H=56, W=56, N=64.
// Output: (B, A*H*W, N) fp32 IoU matrix.
//
// R4 = R3 with nontemporal stores removed (plain global_store_dwordx4,
// same write path as the 6.4 TB/s fill kernel) and the phase-2 loop fully
// unrolled (16 outstanding stores, no loop-carried deps).
//
// Design: two-phase block, wide stores.
//   Phase 1: 192 threads decode 192 proposals (one batch per block) into LDS
//            as {x0,y0,x1,y1} float4.
//   Phase 2: wave w owns proposals [w*64, w*64+64). Lane L: q=L>>4 selects
//            one of 4 proposals per iteration, g=L&15 selects bboxes 4g..4g+3.
//            Per iteration: one ds_read_b128 (broadcast x16) + ~52 VALU
//            + one global_store_dwordx4 -> contiguous 1KB per wave-inst,
//            256 outputs. 16 iterations cover the wave's 64 rows.
// Block=192 because 28224 (proposals/batch) = 147*192 -> no batch straddle.

constexpr int B_ = 16;
constexpr int A_ = 9;
constexpr int H_ = 56;
constexpr int W_ = 56;
constexpr int N_ = 64;
constexpr int HW_ = H_ * W_;            // 3136
constexpr int P_ = A_ * HW_;            // 28224 proposals per batch
constexpr int BLOCK = 192;              // 3 waves
constexpr int BLKS_PER_BATCH = P_ / BLOCK;  // 147

typedef float floatx4 __attribute__((ext_vector_type(4)));

__global__ __launch_bounds__(BLOCK) void ssd_iou_kernel(
    const float* __restrict__ anc,      // (A,2)
    const float* __restrict__ grid,     // (B,H,W,2)
    const float* __restrict__ offsets,  // (B,A,H,W,4)
    const float* __restrict__ bboxes,   // (B,N,5)
    float* __restrict__ out)            // (B, P, N)
{
    __shared__ float4 s_box[BLOCK];

    const int t  = threadIdx.x;
    const int b  = blockIdx.x / BLKS_PER_BATCH;           // batch (uniform)
    const int lb = blockIdx.x - b * BLKS_PER_BATCH;       // block within batch
    const int p0 = lb * BLOCK;                            // first local proposal

    // ---- Phase 1: decode one proposal per thread into LDS ----
    {
        const int lp = p0 + t;               // local proposal id in batch
        const int a  = lp / HW_;
        const int hw = lp - a * HW_;
        const int gp = b * P_ + lp;          // global proposal id

        const float4 off = reinterpret_cast<const float4*>(offsets)[gp];
        const float2 g   = reinterpret_cast<const float2*>(grid)[b * HW_ + hw];
        const float  aw  = anc[2 * a + 0];
        const float  ah  = anc[2 * a + 1];

        const float xc = g.x + off.x;
        const float yc = g.y + off.y;
        const float wp = aw * __expf(off.z);
        const float hp = ah * __expf(off.w);

        float4 box;
        box.x = xc - 0.5f * wp;   // x0
        box.y = yc - 0.5f * hp;   // y0
        box.z = xc + 0.5f * wp;   // x1
        box.w = yc + 0.5f * hp;   // y1
        s_box[t] = box;
    }
    __syncthreads();

    // ---- Phase 2 ----
    const int wave = t >> 6;
    const int lane = t & 63;
    const int q    = lane >> 4;   // proposal sub-index within group of 4
    const int g    = lane & 15;   // bbox group: bboxes 4g..4g+3

    // Per-lane bbox constants (4 boxes). 20KB total -> L1-resident.
    float bx0[4], by0[4], bx1[4], by1[4], aob[4];
    #pragma unroll
    for (int k = 0; k < 4; ++k) {
        const float* bb = bboxes + ((size_t)(b * N_ + 4 * g + k)) * 5;
        bx0[k] = bb[0];
        by0[k] = bb[1];
        bx1[k] = bb[2];
        by1[k] = bb[3];
        aob[k] = (bx1[k] - bx0[k]) * (by1[k] - by0[k]);
    }

    const int pbase = wave * 64;
    // out row for proposal p = pbase+4j+q, columns 4g..4g+3
    float* obase = out + ((size_t)(b * P_ + p0 + pbase + q)) * N_ + 4 * g;

    #pragma unroll
    for (int j = 0; j < 16; ++j) {
        const float4 pr = s_box[pbase + 4 * j + q];
        const float aop = (pr.z - pr.x) * (pr.w - pr.y);

        floatx4 res;
        #pragma unroll
        for (int k = 0; k < 4; ++k) {
            const float tlx = fmaxf(pr.x, bx0[k]);
            const float tly = fmaxf(pr.y, by0[k]);
            const float brx = fminf(pr.z, bx1[k]);
            const float bry = fminf(pr.w, by1[k]);

            const float iw  = fmaxf(brx - tlx, 0.0f);
            const float ih  = fmaxf(bry - tly, 0.0f);
            const float aoi = iw * ih;

            const float denom = aop + aob[k] - aoi;
            res[k] = aoi * __builtin_amdgcn_rcpf(denom);
        }

        *reinterpret_cast<floatx4*>(obase + (size_t)(4 * j) * N_) = res;
    }
}

extern "C" void kernel_launch(void* const* d_in, const int* in_sizes, int n_in,
                              void* d_out, int out_size, void* d_ws, size_t ws_size,
                              hipStream_t stream) {
    const float* anc     = (const float*)d_in[0];
    const float* grid    = (const float*)d_in[1];
    const float* offsets = (const float*)d_in[2];
    const float* bboxes  = (const float*)d_in[3];
    float* out = (float*)d_out;

    const int nblocks = B_ * BLKS_PER_BATCH;   // 2352
    ssd_iou_kernel<<<nblocks, BLOCK, 0, stream>>>(anc, grid, offsets, bboxes, out);
}